// Round 6
// baseline (716.212 us; speedup 1.0000x reference)
//
#include <hip/hip_runtime.h>

#define KSTATE 64
#define NSAMP  1024

__device__ __forceinline__ float bcast0(float x) {
  return __int_as_float(__builtin_amdgcn_readfirstlane(__float_as_int(x)));
}

// One wave (64 threads): row-softmax of T -> expT, log_softmax(pi) -> log_pi, zero out.
__global__ __launch_bounds__(64) void hmm_preproc(
    const float* __restrict__ pi, const float* __restrict__ T,
    float* __restrict__ expT, float* __restrict__ log_pi,
    float* __restrict__ out) {
  const int lane = threadIdx.x;
  float m = -3.4e38f;
  for (int k = 0; k < KSTATE; ++k) m = fmaxf(m, T[lane * KSTATE + k]);
  float s = 0.f;
  for (int k = 0; k < KSTATE; ++k) s += __expf(T[lane * KSTATE + k] - m);
  float inv = 1.0f / s;
  for (int k = 0; k < KSTATE; ++k)
    expT[lane * KSTATE + k] = __expf(T[lane * KSTATE + k] - m) * inv;
  float x = pi[lane];
  float mm = x;
  #pragma unroll
  for (int off = 32; off >= 1; off >>= 1) mm = fmaxf(mm, __shfl_xor(mm, off, 64));
  float e = __expf(x - mm);
  #pragma unroll
  for (int off = 32; off >= 1; off >>= 1) e += __shfl_xor(e, off, 64);
  log_pi[lane] = x - mm - __logf(e);
  if (lane == 0) out[0] = 0.f;  // harness poisons d_out; we atomicAdd into it
}

// TWO sequences per wave, phase-interleaved, scaled-linear forward recurrence.
//
// All broadcast mechanisms are latency-bound at ~580-660 cyc/step with the
// hardware idle (1 wave/SIMD, serial chain). Uniform ds_read_b128 has the
// LOWEST issue cost (~205 cyc: 17 DS + 64 fma + glue) but exposes ~450 cyc
// of LDS write->read latency + delivery. Fix: interleave a second sequence;
// X's LDS window is covered by Y's compute phase and vice versa.
// Each PHASE: consume Q (broadcasts issued end of previous own phase) ->
// 64 fma -> tree -> a -> ds_write -> issue 16 uniform ds_read_b128 for the
// next own phase. sched_barrier(0) pins the read-issue at phase end.
// Renorm never modifies `a` after its write: the scale folds into the NEXT
// step's E factor, so LDS and register copies stay coherent.
__global__ __launch_bounds__(64, 1) void hmm_forward(
    const float* __restrict__ log_pdf,
    const float* __restrict__ expT,
    const float* __restrict__ log_pi,
    float* __restrict__ out, int N) {
  __shared__ __align__(16) float abX[KSTATE];
  __shared__ __align__(16) float abY[KSTATE];
  const int lane = threadIdx.x & 63;
  const int bX = blockIdx.x * 2;
  const int bY = bX + 1;

  // tcol[j] = expT[j][lane]  (column `lane` of the transition matrix)
  float tcol[KSTATE];
  #pragma unroll
  for (int j = 0; j < KSTATE; ++j) tcol[j] = expT[j * KSTATE + lane];

  const float* lpX = log_pdf + (size_t)lane * (size_t)N + (size_t)bX * NSAMP;
  const float* lpY = log_pdf + (size_t)lane * (size_t)N + (size_t)bY * NSAMP;

  float4 vX = *(const float4*)(lpX);       // current group (t=0..3)
  float4 rX1 = *(const float4*)(lpX + 4);  // next group
  float4 vY = *(const float4*)(lpY);
  float4 rY1 = *(const float4*)(lpY + 4);

  float xX = vX.x + log_pi[lane];
  float CX = bcast0(xX);
  float aX = __expf(xX - CX);
  float xY = vY.x + log_pi[lane];
  float CY = bcast0(xY);
  float aY = __expf(xY - CY);

  float4 QX[16], QY[16];
  // bootstrap: publish a(t=0) and issue broadcast reads for step 1
  abX[lane] = aX;
  #pragma unroll
  for (int q = 0; q < 16; ++q) QX[q] = *(const float4*)(abX + 4 * q);
  abY[lane] = aY;
  #pragma unroll
  for (int q = 0; q < 16; ++q) QY[q] = *(const float4*)(abY + 4 * q);
  __builtin_amdgcn_sched_barrier(0);

#define PHASE(A, AB, Q, E) do {                                               \
    float c0 = Q[0].x * tcol[0],  c1 = Q[0].y * tcol[1];                      \
    float c2 = Q[0].z * tcol[2],  c3 = Q[0].w * tcol[3];                      \
    float c4 = Q[1].x * tcol[4],  c5 = Q[1].y * tcol[5];                      \
    float c6 = Q[1].z * tcol[6],  c7 = Q[1].w * tcol[7];                      \
    _Pragma("unroll")                                                         \
    for (int q = 2; q < 16; q += 2) {                                         \
      c0 = fmaf(Q[q].x,     tcol[4*q+0], c0);                                 \
      c1 = fmaf(Q[q].y,     tcol[4*q+1], c1);                                 \
      c2 = fmaf(Q[q].z,     tcol[4*q+2], c2);                                 \
      c3 = fmaf(Q[q].w,     tcol[4*q+3], c3);                                 \
      c4 = fmaf(Q[q+1].x,   tcol[4*q+4], c4);                                 \
      c5 = fmaf(Q[q+1].y,   tcol[4*q+5], c5);                                 \
      c6 = fmaf(Q[q+1].z,   tcol[4*q+6], c6);                                 \
      c7 = fmaf(Q[q+1].w,   tcol[4*q+7], c7);                                 \
    }                                                                         \
    float sA = (c0 + c1) + (c2 + c3);                                         \
    float sB = (c4 + c5) + (c6 + c7);                                         \
    A = (sA + sB) * (E);                                                      \
    AB[lane] = A;                              /* publish a(t+1) */           \
    _Pragma("unroll")                                                         \
    for (int q = 0; q < 16; ++q) Q[q] = *(const float4*)(AB + 4 * q);         \
    __builtin_amdgcn_sched_barrier(0);                                        \
  } while (0)

  // Renorm: does NOT touch A (already published); scale applies to the next
  // step's E. C accrues log(c) with c = broadcast a[0].
#define RENORM(A, Cc, S) do {                                                 \
    float c_ = bcast0(A);                                                     \
    S = __builtin_amdgcn_rcpf(c_);                                            \
    Cc += __logf(c_);                                                         \
  } while (0)

  float sXs, sYs;

  {  // group 0: steps t = 1..3
    float eX1 = __expf(vX.y), eX2 = __expf(vX.z), eX3 = __expf(vX.w);
    float eY1 = __expf(vY.y), eY2 = __expf(vY.z), eY3 = __expf(vY.w);
    PHASE(aX, abX, QX, eX1); PHASE(aY, abY, QY, eY1);
    PHASE(aX, abX, QX, eX2); PHASE(aY, abY, QY, eY2);
    PHASE(aX, abX, QX, eX3); PHASE(aY, abY, QY, eY3);
    RENORM(aX, CX, sXs); RENORM(aY, CY, sYs);
  }

  const int NG = NSAMP / 4;
  for (int g = 1; g < NG; ++g) {
    vX = rX1; vY = rY1;
    int gn = (g + 1 < NG) ? (g + 1) : (NG - 1);
    rX1 = *(const float4*)(lpX + 4 * gn);
    rY1 = *(const float4*)(lpY + 4 * gn);
    float eX0 = __expf(vX.x) * sXs, eX1 = __expf(vX.y);
    float eX2 = __expf(vX.z),       eX3 = __expf(vX.w);
    float eY0 = __expf(vY.x) * sYs, eY1 = __expf(vY.y);
    float eY2 = __expf(vY.z),       eY3 = __expf(vY.w);
    PHASE(aX, abX, QX, eX0); PHASE(aY, abY, QY, eY0);
    PHASE(aX, abX, QX, eX1); PHASE(aY, abY, QY, eY1);
    PHASE(aX, abX, QX, eX2); PHASE(aY, abY, QY, eY2);
    PHASE(aX, abX, QX, eX3); PHASE(aY, abY, QY, eY3);
    RENORM(aX, CX, sXs); RENORM(aY, CY, sYs);
  }
#undef PHASE
#undef RENORM

  // Epilogue. Final RENORM set s = rcp(c_final) and added log(c_final) to C,
  // but a was never rescaled: out += C + log(s * sum_k a[k]) compensates.
  float s1 = aX;
  #pragma unroll
  for (int off = 32; off >= 1; off >>= 1) s1 += __shfl_xor(s1, off, 64);
  float s2 = aY;
  #pragma unroll
  for (int off = 32; off >= 1; off >>= 1) s2 += __shfl_xor(s2, off, 64);
  if (lane == 0) {
    atomicAdd(out, (CX + __logf(s1 * sXs)) + (CY + __logf(s2 * sYs)));
  }
}

extern "C" void kernel_launch(void* const* d_in, const int* in_sizes, int n_in,
                              void* d_out, int out_size, void* d_ws, size_t ws_size,
                              hipStream_t stream) {
  const float* log_pdf = (const float*)d_in[0];
  const float* pi      = (const float*)d_in[1];
  const float* T       = (const float*)d_in[2];
  float* out = (float*)d_out;

  float* expT   = (float*)d_ws;              // 64*64 floats
  float* log_pi = expT + KSTATE * KSTATE;    // 64 floats

  const int N = in_sizes[0] / KSTATE;        // 1048576
  const int B = N / NSAMP;                   // 1024 sequences

  hipLaunchKernelGGL(hmm_preproc, dim3(1), dim3(64), 0, stream,
                     pi, T, expT, log_pi, out);
  hipLaunchKernelGGL(hmm_forward, dim3(B / 2), dim3(64), 0, stream,
                     log_pdf, expT, log_pi, out, N);
}

// Round 8
// 535.105 us; speedup vs baseline: 1.3385x; 1.3385x over previous
//
#include <hip/hip_runtime.h>

#define KSTATE 64
#define NSAMP  1024

__device__ __forceinline__ float bcast0(float x) {
  return __int_as_float(__builtin_amdgcn_readfirstlane(__float_as_int(x)));
}
__device__ __forceinline__ float rlane(float x, int l) {
  return __int_as_float(__builtin_amdgcn_readlane(__float_as_int(x), l));
}

// One wave (64 threads): row-softmax of T -> expT, log_softmax(pi) -> log_pi, zero out.
__global__ __launch_bounds__(64) void hmm_preproc(
    const float* __restrict__ pi, const float* __restrict__ T,
    float* __restrict__ expT, float* __restrict__ log_pi,
    float* __restrict__ out) {
  const int lane = threadIdx.x;
  float m = -3.4e38f;
  for (int k = 0; k < KSTATE; ++k) m = fmaxf(m, T[lane * KSTATE + k]);
  float s = 0.f;
  for (int k = 0; k < KSTATE; ++k) s += __expf(T[lane * KSTATE + k] - m);
  float inv = 1.0f / s;
  for (int k = 0; k < KSTATE; ++k)
    expT[lane * KSTATE + k] = __expf(T[lane * KSTATE + k] - m) * inv;
  float x = pi[lane];
  float mm = x;
  #pragma unroll
  for (int off = 32; off >= 1; off >>= 1) mm = fmaxf(mm, __shfl_xor(mm, off, 64));
  float e = __expf(x - mm);
  #pragma unroll
  for (int off = 32; off >= 1; off >>= 1) e += __shfl_xor(e, off, 64);
  log_pi[lane] = x - mm - __logf(e);
  if (lane == 0) out[0] = 0.f;  // harness poisons d_out; we atomicAdd into it
}

// One wave per sequence, scaled-linear-domain forward recurrence.
//
// Round-7 (resubmit; prior bench was an infra failure): HYBRID broadcast,
// chain-optimal split. Calibration (r0-r5 fits):
//   write->read-data window W ~ 180 cyc; uniform ds_read_b128 ~23 cyc each,
//   in-order; readlane+fma pair ~10.3 cyc (issue); plain fma 2 cyc.
// Interleaving more sequences per wave CANNOT beat 1024*chain (r6 lesson:
// wall = steps * max(M*busy, chain)), so the only lever is the chain:
//   j = 0..31  via readlane->fma: zero latency, fills the LDS window,
//   j = 32..63 via 8 wave-uniform ds_read_b128 issued right after the write.
// chain ~ max(32*10.3, W + 8*23) + tail ~ 410 cyc/step vs 586 (r0) / 660 (r5).
// Only 9 DS ops outstanding -> countable lgkmcnt, compiler staggers waits.
__global__ __launch_bounds__(256, 1) void hmm_forward(
    const float* __restrict__ log_pdf,
    const float* __restrict__ expT,
    const float* __restrict__ log_pi,
    float* __restrict__ out, int N) {
  __shared__ __align__(16) float abuf[4][KSTATE];  // wave-private rows
  const int lane = threadIdx.x & 63;
  const int wave = threadIdx.x >> 6;
  const int b = blockIdx.x * 4 + wave;
  float* ab = abuf[wave];

  // tcol[j] = expT[j][lane]  (column `lane` of the transition matrix)
  float tcol[KSTATE];
  #pragma unroll
  for (int j = 0; j < KSTATE; ++j) tcol[j] = expT[j * KSTATE + lane];

  const float* lp = log_pdf + (size_t)lane * (size_t)N + (size_t)b * NSAMP;

  float4 v0 = *(const float4*)(lp);        // group 0 (t=0..3)
  float4 r1 = *(const float4*)(lp + 4);
  float4 r2 = *(const float4*)(lp + 8);
  float4 r3 = *(const float4*)(lp + 12);

  float x0 = v0.x + log_pi[lane];
  float C = bcast0(x0);
  float a = __expf(x0 - C);

#define STEP(E) do {                                                          \
    ab[lane] = a;                              /* ds_write_b32 */             \
    float4 Q0 = *(const float4*)(ab + 32);     /* 8x uniform ds_read_b128  */ \
    float4 Q1 = *(const float4*)(ab + 36);     /* broadcast a[32..63]      */ \
    float4 Q2 = *(const float4*)(ab + 40);                                    \
    float4 Q3 = *(const float4*)(ab + 44);                                    \
    float4 Q4 = *(const float4*)(ab + 48);                                    \
    float4 Q5 = *(const float4*)(ab + 52);                                    \
    float4 Q6 = *(const float4*)(ab + 56);                                    \
    float4 Q7 = *(const float4*)(ab + 60);                                    \
    __builtin_amdgcn_sched_barrier(0);                                        \
    /* rl front: j = 0..31 on the VALU, covers the LDS window+delivery */     \
    float c0 = rlane(a, 0) * tcol[0], c1 = rlane(a, 1) * tcol[1];             \
    float c2 = rlane(a, 2) * tcol[2], c3 = rlane(a, 3) * tcol[3];             \
    float c4 = rlane(a, 4) * tcol[4], c5 = rlane(a, 5) * tcol[5];             \
    float c6 = rlane(a, 6) * tcol[6], c7 = rlane(a, 7) * tcol[7];             \
    _Pragma("unroll")                                                         \
    for (int q = 8; q < 32; q += 8) {                                         \
      c0 = fmaf(rlane(a, q + 0), tcol[q + 0], c0);                            \
      c1 = fmaf(rlane(a, q + 1), tcol[q + 1], c1);                            \
      c2 = fmaf(rlane(a, q + 2), tcol[q + 2], c2);                            \
      c3 = fmaf(rlane(a, q + 3), tcol[q + 3], c3);                            \
      c4 = fmaf(rlane(a, q + 4), tcol[q + 4], c4);                            \
      c5 = fmaf(rlane(a, q + 5), tcol[q + 5], c5);                            \
      c6 = fmaf(rlane(a, q + 6), tcol[q + 6], c6);                            \
      c7 = fmaf(rlane(a, q + 7), tcol[q + 7], c7);                            \
    }                                                                         \
    __builtin_amdgcn_sched_barrier(0);                                        \
    /* back: j = 32..63, consume Q in delivery order (staggered lgkmcnt) */   \
    c0 = fmaf(Q0.x, tcol[32], c0); c1 = fmaf(Q0.y, tcol[33], c1);             \
    c2 = fmaf(Q0.z, tcol[34], c2); c3 = fmaf(Q0.w, tcol[35], c3);             \
    c4 = fmaf(Q1.x, tcol[36], c4); c5 = fmaf(Q1.y, tcol[37], c5);             \
    c6 = fmaf(Q1.z, tcol[38], c6); c7 = fmaf(Q1.w, tcol[39], c7);             \
    c0 = fmaf(Q2.x, tcol[40], c0); c1 = fmaf(Q2.y, tcol[41], c1);             \
    c2 = fmaf(Q2.z, tcol[42], c2); c3 = fmaf(Q2.w, tcol[43], c3);             \
    c4 = fmaf(Q3.x, tcol[44], c4); c5 = fmaf(Q3.y, tcol[45], c5);             \
    c6 = fmaf(Q3.z, tcol[46], c6); c7 = fmaf(Q3.w, tcol[47], c7);             \
    c0 = fmaf(Q4.x, tcol[48], c0); c1 = fmaf(Q4.y, tcol[49], c1);             \
    c2 = fmaf(Q4.z, tcol[50], c2); c3 = fmaf(Q4.w, tcol[51], c3);             \
    c4 = fmaf(Q5.x, tcol[52], c4); c5 = fmaf(Q5.y, tcol[53], c5);             \
    c6 = fmaf(Q5.z, tcol[54], c6); c7 = fmaf(Q5.w, tcol[55], c7);             \
    c0 = fmaf(Q6.x, tcol[56], c0); c1 = fmaf(Q6.y, tcol[57], c1);             \
    c2 = fmaf(Q6.z, tcol[58], c2); c3 = fmaf(Q6.w, tcol[59], c3);             \
    c4 = fmaf(Q7.x, tcol[60], c4); c5 = fmaf(Q7.y, tcol[61], c5);             \
    c6 = fmaf(Q7.z, tcol[62], c6); c7 = fmaf(Q7.w, tcol[63], c7);             \
    float sA = (c0 + c1) + (c2 + c3);                                         \
    float sB = (c4 + c5) + (c6 + c7);                                         \
    a = (sA + sB) * (E);                                                      \
  } while (0)

  // Renorm every 4 steps (range analysis: 4-step growth/decay stays well
  // inside fp32; identical math to the verified earlier rounds).
#define RENORM() do {                                                         \
    float c = bcast0(a);                                                      \
    a = a * __builtin_amdgcn_rcpf(c);                                         \
    C += __logf(c);                                                           \
  } while (0)

  {  // steps t = 1..3 from group 0
    float e1 = __expf(v0.y), e2 = __expf(v0.z), e3 = __expf(v0.w);
    STEP(e1); STEP(e2); STEP(e3);
    RENORM();
  }

  const int NG = NSAMP / 4;
  for (int g = 1; g < NG; ++g) {
    float4 v = r1; r1 = r2; r2 = r3;
    int gn = (g + 3 < NG) ? (g + 3) : (NG - 1);
    r3 = *(const float4*)(lp + 4 * gn);
    float e0 = __expf(v.x), e1 = __expf(v.y), e2 = __expf(v.z), e3 = __expf(v.w);
    STEP(e0); STEP(e1); STEP(e2); STEP(e3);
    RENORM();
  }
#undef STEP
#undef RENORM

  // out += C + log(sum_k a[k])
  float s = a;
  #pragma unroll
  for (int off = 32; off >= 1; off >>= 1) s += __shfl_xor(s, off, 64);
  if (lane == 0) atomicAdd(out, C + __logf(s));
}

extern "C" void kernel_launch(void* const* d_in, const int* in_sizes, int n_in,
                              void* d_out, int out_size, void* d_ws, size_t ws_size,
                              hipStream_t stream) {
  const float* log_pdf = (const float*)d_in[0];
  const float* pi      = (const float*)d_in[1];
  const float* T       = (const float*)d_in[2];
  float* out = (float*)d_out;

  float* expT   = (float*)d_ws;              // 64*64 floats
  float* log_pi = expT + KSTATE * KSTATE;    // 64 floats

  const int N = in_sizes[0] / KSTATE;        // 1048576
  const int B = N / NSAMP;                   // 1024 sequences

  hipLaunchKernelGGL(hmm_preproc, dim3(1), dim3(64), 0, stream,
                     pi, T, expT, log_pi, out);
  hipLaunchKernelGGL(hmm_forward, dim3(B / 4), dim3(256), 0, stream,
                     log_pdf, expT, log_pi, out, N);
}